// Round 10
// baseline (608.440 us; speedup 1.0000x reference)
//
#include <hip/hip_runtime.h>

#define N_TOK 16384
#define HIDN  768
#define MIDN  5376
#define COMBN 3840
#define NH    12
#define DHD   64
#define CHUNK 256
#define WIN   256

typedef short s16x8 __attribute__((ext_vector_type(8)));
typedef short s16x4 __attribute__((ext_vector_type(4)));
typedef float f32x4 __attribute__((ext_vector_type(4)));

__device__ __forceinline__ float bf2f(unsigned short u){
  union { unsigned u; float f; } x; x.u = ((unsigned)u) << 16; return x.f;
}
__device__ __forceinline__ unsigned short f2bf(float f){
  union { float f; unsigned u; } x; x.f = f;
  unsigned r = x.u + 0x7fffu + ((x.u >> 16) & 1u);
  return (unsigned short)(r >> 16);
}
__device__ __forceinline__ float gelu_fast(float x){
  float u = -1.5957691216057308f * (x + 0.044715f * x * x * x);
  return x / (1.f + __expf(u));
}
__device__ __forceinline__ void glds16(const void* g, void* l){
  __builtin_amdgcn_global_load_lds(
      (const __attribute__((address_space(1))) unsigned*)g,
      (__attribute__((address_space(3))) unsigned*)l, 16, 0, 0);
}

// ------- transpose + downcast: in fp32 [R][Cc] -> out bf16 [Cc][R] -------
__global__ __launch_bounds__(256) void transpose_f2b(
    const float* __restrict__ in, unsigned short* __restrict__ out,
    int R, int Cc)
{
  __shared__ short t[64 * 72];
  const int tid = threadIdx.x;
  const int r0 = blockIdx.y * 64, c0 = blockIdx.x * 64;
  #pragma unroll
  for (int rep = 0; rep < 4; rep++){
    int v = tid + 256 * rep;
    int r = v >> 4, s = v & 15;
    float4 d = *(const float4*)(in + (size_t)(r0 + r) * Cc + c0 + s * 4);
    s16x4 o = { (short)f2bf(d.x), (short)f2bf(d.y), (short)f2bf(d.z), (short)f2bf(d.w) };
    *(s16x4*)(t + r * 72 + s * 4) = o;
  }
  __syncthreads();
  #pragma unroll
  for (int rep = 0; rep < 2; rep++){
    int v = tid + 256 * rep;
    int c = v & 63, s2 = v >> 6;
    s16x8 d;
    #pragma unroll
    for (int j = 0; j < 8; j++) d[j] = t[(s2 * 8 + j) * 72 + c];
    *(s16x8*)(out + (size_t)(c0 + c) * R + r0 + s2 * 8) = d;
  }
}

// ------- layernorm: fp32 in -> bf16 out, one wave per row -------
__global__ __launch_bounds__(256) void ln_kernel(
    const float* __restrict__ x, const float* __restrict__ sc,
    const float* __restrict__ ofs, unsigned short* __restrict__ xn)
{
  const int lane = threadIdx.x & 63, wv = threadIdx.x >> 6;
  const int row = blockIdx.x * 4 + wv;
  const float4* xr = (const float4*)(x + (size_t)row * HIDN);
  float4 vals[3];
  float sum = 0.f, sq = 0.f;
  #pragma unroll
  for (int j = 0; j < 3; j++){
    vals[j] = xr[lane + 64 * j];
    sum += vals[j].x + vals[j].y + vals[j].z + vals[j].w;
    sq  += vals[j].x * vals[j].x + vals[j].y * vals[j].y
         + vals[j].z * vals[j].z + vals[j].w * vals[j].w;
  }
  #pragma unroll
  for (int o = 1; o < 64; o <<= 1){ sum += __shfl_xor(sum, o); sq += __shfl_xor(sq, o); }
  const float mu = sum * (1.f / HIDN);
  const float rs = rsqrtf(fmaxf(sq * (1.f / HIDN) - mu * mu, 0.f) + 1e-5f);
  s16x4* xo = (s16x4*)(xn + (size_t)row * HIDN);
  const float4* scp = (const float4*)sc;
  const float4* ofp = (const float4*)ofs;
  #pragma unroll
  for (int j = 0; j < 3; j++){
    int p = lane + 64 * j;
    float4 s = scp[p], o = ofp[p];
    s16x4 w;
    w[0] = (short)f2bf((vals[j].x - mu) * rs * s.x + o.x);
    w[1] = (short)f2bf((vals[j].y - mu) * rs * s.y + o.y);
    w[2] = (short)f2bf((vals[j].z - mu) * rs * s.z + o.z);
    w[3] = (short)f2bf((vals[j].w - mu) * rs * s.w + o.w);
    xo[p] = w;
  }
}

// ============================================================================
// R10 GEMM pipe: 128x128 tile, 256 threads = 4 waves (2Mx2N), acc[4][4];
// BK=32, 4 LDS buffers (4 x 16 KiB = 64 KiB -> 2 blocks/CU), depth-3.5
// pipeline: stage(t+4) per phase, counted vmcnt(12), 1 barrier/phase,
// frags for t+1 ds_read at the phase tail (a full MFMA cluster ahead).
//
// In-flight bookkeeping (4 loads per stage): at phase t tail, staged tiles
// t+2,t+3,t+4 are in flight = 12 -> vmcnt(12) forces tile t+1 landed.
// Issue-to-wait window for a tile: 3.5 phases (~500-800 cyc) -- covers HBM
// first-touch latency (R8's 2-phase window only covered L2 hits).
// WAR-safety of stage(t+4) -> buf[t&3]: tile t's ds_reads completed before
// phase-t MFMAs issued (lgkmcnt dependency), which precede phase-t's
// barrier, which precedes this stage's issue in phase t+1. Verified swizzle
// (R6-R9, conflicts=0): 64B rows, phys seg = seg^((row>>1)&3), inverse on
// global source col ksw = ((tid&3)^((tid>>3)&3))*8 elems.
// ============================================================================
template<int K>
__device__ __forceinline__ void gemm_pipe3(
    const unsigned short* __restrict__ A, const unsigned short* __restrict__ BT,
    short* SM,   // 32768 shorts = 64 KiB: buf b at b*16384B; A +0, B +8192
    int tid, int quad, int l15, int wr, int wc, int m0, int n0,
    f32x4 acc[4][4])
{
  constexpr int T = K / 32;
  char* const SMc = (char*)SM;
  const int srow = tid >> 2;
  const int ksw  = ((tid & 3) ^ ((tid >> 3) & 3)) * 8;
  const unsigned short* Ap = A  + (size_t)(m0 + srow) * K + ksw;
  const unsigned short* Bp = BT + (size_t)(n0 + srow) * K + ksw;
  const size_t hstep = (size_t)64 * K;

  const int segx = ((quad ^ ((l15 >> 1) & 3)) << 4);
  int offA[4], offB[4];
  #pragma unroll
  for (int mf = 0; mf < 4; mf++) offA[mf] = (wr * 64 + mf * 16 + l15) * 64 + segx;
  #pragma unroll
  for (int nf = 0; nf < 4; nf++) offB[nf] = (wc * 64 + nf * 16 + l15) * 64 + segx;

  auto stage = [&](int tt){
    const int b = tt & 3;
    char* Ad = SMc + b * 16384 + tid * 16;
    char* Bd = SMc + b * 16384 + 8192 + tid * 16;
    glds16(Ap + tt * 32,         Ad);
    glds16(Ap + tt * 32 + hstep, Ad + 4096);
    glds16(Bp + tt * 32,         Bd);
    glds16(Bp + tt * 32 + hstep, Bd + 4096);
  };

  s16x8 af[4], bf[4];
  auto rdfrags = [&](int b){
    const char* Ab = SMc + b * 16384;
    const char* Bb = SMc + b * 16384 + 8192;
    #pragma unroll
    for (int i = 0; i < 4; i++) af[i] = *(const s16x8*)(Ab + offA[i]);
    #pragma unroll
    for (int j = 0; j < 4; j++) bf[j] = *(const s16x8*)(Bb + offB[j]);
  };

  stage(0); stage(1); stage(2); stage(3);
  asm volatile("s_waitcnt vmcnt(12)" ::: "memory");   // tile 0 landed; 1-3 fly
  asm volatile("s_barrier" ::: "memory");
  rdfrags(0);

  #pragma unroll 4
  for (int t = 0; t < T; ++t){
    if (t + 4 < T) stage(t + 4);
    __builtin_amdgcn_s_setprio(1);
    #pragma unroll
    for (int i = 0; i < 4; i++)
      #pragma unroll
      for (int j = 0; j < 4; j++)
        acc[i][j] = __builtin_amdgcn_mfma_f32_16x16x32_bf16(af[i], bf[j], acc[i][j], 0, 0, 0);
    __builtin_amdgcn_s_setprio(0);
    if (t + 1 < T){
      if (t + 4 < T)      { asm volatile("s_waitcnt vmcnt(12)" ::: "memory"); }
      else if (t + 3 < T) { asm volatile("s_waitcnt vmcnt(8)"  ::: "memory"); }
      else if (t + 2 < T) { asm volatile("s_waitcnt vmcnt(4)"  ::: "memory"); }
      else                { asm volatile("s_waitcnt vmcnt(0)"  ::: "memory"); }
      asm volatile("s_barrier" ::: "memory");
      rdfrags((t + 1) & 3);
    }
  }
}

// ------- GEMM1: [16384x768] x [5376x768]^T -> q(rope)/k(rope)/v/comb(gelu) ---
__global__ __launch_bounds__(256, 2) void gemm1_k(
    const unsigned short* __restrict__ A, const unsigned short* __restrict__ BT,
    const float* __restrict__ bias,
    const float* __restrict__ psin, const float* __restrict__ pcos,
    unsigned short* __restrict__ qb, unsigned short* __restrict__ kb,
    unsigned short* __restrict__ vb, unsigned short* __restrict__ comb)
{
  __shared__ short SM[32768];
  const int tid = threadIdx.x, lane = tid & 63, wv = tid >> 6;
  const int quad = lane >> 4, l15 = lane & 15;
  const int wr = wv >> 1, wc = wv & 1;

  // supertile remap (measured best in R8): GROUP_M=16 m-rows per super-row
  const int nbx = gridDim.x;                    // 42
  const int bid = blockIdx.x + blockIdx.y * nbx;
  const int GM = 16;
  const int group = bid / (GM * nbx);
  const int rem   = bid % (GM * nbx);
  const int m0 = (group * GM + (rem % GM)) * 128;
  const int n0 = (rem / GM) * 128;

  f32x4 acc[4][4];
  #pragma unroll
  for (int i = 0; i < 4; i++)
    #pragma unroll
    for (int j = 0; j < 4; j++) acc[i][j] = (f32x4){0.f,0.f,0.f,0.f};

  gemm_pipe3<HIDN>(A, BT, SM, tid, quad, l15, wr, wc, m0, n0, acc);

  // block-uniform output class (boundaries 768/1536/2304 are multiples of 128)
  unsigned short* dstb; int cb; int cls;
  if (n0 < 768)       { dstb = qb;   cb = n0;        cls = 0; }
  else if (n0 < 1536) { dstb = kb;   cb = n0 - 768;  cls = 1; }
  else if (n0 < 2304) { dstb = vb;   cb = n0 - 1536; cls = 2; }
  else                { dstb = comb; cb = n0 - 1536; cls = 3; }
  const int rowstride = (cls == 3) ? COMBN : HIDN;

  float bsv[4];
  #pragma unroll
  for (int nf = 0; nf < 4; nf++) bsv[nf] = bias[n0 + wc * 64 + nf * 16 + l15];

  if (cls <= 1){
    // q/k: fused RoPE (+1/8 scale for q). Pair partner of col c is c^1 ->
    // lane l15^1 (same nf): one shfl_xor. d = col%64 = nf*16+l15, so sin/cos
    // reads are 64-lane coalesced and L2-hot (4 MB tables).
    const float qscale = (cls == 0) ? 0.125f : 1.0f;
    #pragma unroll
    for (int mf = 0; mf < 4; mf++){
      #pragma unroll
      for (int r = 0; r < 4; r++){
        const int row = m0 + wr * 64 + mf * 16 + quad * 4 + r;
        unsigned short* rp = dstb + (size_t)row * rowstride + cb + wc * 64;
        const float* sp = psin + (size_t)row * DHD;
        const float* cp = pcos + (size_t)row * DHD;
        #pragma unroll
        for (int nf = 0; nf < 4; nf++){
          const int d = nf * 16 + l15;
          float v = acc[mf][nf][r] + bsv[nf];
          float vp = __shfl_xor(v, 1);
          const float s = sp[d], c = cp[d];
          float o = (l15 & 1) ? (v * c + vp * s) : (v * c - vp * s);
          rp[d] = f2bf(o * qscale);
        }
      }
    }
  } else {
    // v / ff: nf-INNER contiguous 128B row-runs (full-line writes)
    #pragma unroll
    for (int mf = 0; mf < 4; mf++){
      #pragma unroll
      for (int r = 0; r < 4; r++){
        const int row = m0 + wr * 64 + mf * 16 + quad * 4 + r;
        unsigned short* rp = dstb + (size_t)row * rowstride + cb + wc * 64;
        #pragma unroll
        for (int nf = 0; nf < 4; nf++){
          float val = acc[mf][nf][r] + bsv[nf];
          if (cls == 3) val = gelu_fast(val);
          rp[nf * 16 + l15] = f2bf(val);
        }
      }
    }
  }
}

// ------- GEMM2: [16384x3840] x [768x3840]^T + b + xn residual -> fp32 -------
__global__ __launch_bounds__(256, 2) void gemm2_k(
    const unsigned short* __restrict__ A, const unsigned short* __restrict__ BT,
    const float* __restrict__ bias, const unsigned short* __restrict__ xn,
    float* __restrict__ outp)
{
  __shared__ short SM[32768];
  const int tid = threadIdx.x, lane = tid & 63, wv = tid >> 6;
  const int quad = lane >> 4, l15 = lane & 15;
  const int wr = wv >> 1, wc = wv & 1;
  const int n0 = blockIdx.x * 128, m0 = blockIdx.y * 128;

  f32x4 acc[4][4];
  #pragma unroll
  for (int i = 0; i < 4; i++)
    #pragma unroll
    for (int j = 0; j < 4; j++) acc[i][j] = (f32x4){0.f,0.f,0.f,0.f};

  gemm_pipe3<COMBN>(A, BT, SM, tid, quad, l15, wr, wc, m0, n0, acc);

  float bsv[4];
  #pragma unroll
  for (int nf = 0; nf < 4; nf++) bsv[nf] = bias[n0 + wc * 64 + nf * 16 + l15];

  #pragma unroll
  for (int mf = 0; mf < 4; mf++){
    #pragma unroll
    for (int r = 0; r < 4; r++){
      const int row = m0 + wr * 64 + mf * 16 + quad * 4 + r;
      const size_t rb = (size_t)row * HIDN + n0 + wc * 64;
      #pragma unroll
      for (int nf = 0; nf < 4; nf++){
        const size_t o = rb + nf * 16 + l15;
        outp[o] = bf2f(xn[o]) + acc[mf][nf][r] + bsv[nf];
      }
    }
  }
}

// ------- chunked local attention: pre-roped Q/K [tok][768], 64-key tiles -------
__global__ __launch_bounds__(256) void attn_kernel(
    const unsigned short* __restrict__ qb, const unsigned short* __restrict__ kb,
    const unsigned short* __restrict__ vb, unsigned short* __restrict__ comb,
    const int* __restrict__ lenp)
{
  __shared__ short Ks[2][64 * 72];
  __shared__ short Vt[2][64 * 64];
  __shared__ short Ps[4][16 * 72];
  const int tid = threadIdx.x, lane = tid & 63, wv = tid >> 6;
  const int quad = lane >> 4, l15 = lane & 15;
  const int h = blockIdx.y, c = blockIdx.x;
  const unsigned lm = ~((unsigned)lenp[0] - 1u);
  const int i0 = c * CHUNK + wv * 64;
  const unsigned short* qh = qb + h * DHD;
  const unsigned short* kh = kb + h * DHD;
  const unsigned short* vh = vb + h * DHD;

  s16x8 qf[4][2];
  #pragma unroll
  for (int rt = 0; rt < 4; rt++){
    const unsigned short* qr = qh + (size_t)(i0 + rt * 16 + l15) * HIDN;
    qf[rt][0] = *(const s16x8*)(qr + quad * 8);
    qf[rt][1] = *(const s16x8*)(qr + 32 + quad * 8);
  }

  f32x4 O[4][4];
  float mm[4][4], ll[4][4];
  #pragma unroll
  for (int rt = 0; rt < 4; rt++)
    #pragma unroll
    for (int j = 0; j < 4; j++){ O[rt][j] = (f32x4){0,0,0,0}; mm[rt][j] = -1e30f; ll[rt][j] = 0.f; }
  short* myP = &Ps[wv][0];

  const int skey = tid & 63, sseg = tid >> 6;
  const int jb0 = c * CHUNK - 256;
  s16x8 kr[2], vr[2];

  auto issue = [&](int jb){
    if (jb >= 0){
      const unsigned short* kp = kh + (size_t)(jb + skey) * HIDN + sseg * 16;
      const unsigned short* vp = vh + (size_t)(jb + skey) * HIDN + sseg * 16;
      kr[0] = *(const s16x8*)(kp);     kr[1] = *(const s16x8*)(kp + 8);
      vr[0] = *(const s16x8*)(vp);     vr[1] = *(const s16x8*)(vp + 8);
    } else {
      kr[0] = kr[1] = vr[0] = vr[1] = (s16x8){0,0,0,0,0,0,0,0};
    }
  };

  issue(jb0);
  for (int tb = 0; tb < 8; tb++){
    const int jb = jb0 + tb * 64;
    const int buf = tb & 1;
    short* Kb = &Ks[buf][0];
    short* Vb = &Vt[buf][0];
    *(s16x8*)(Kb + skey * 72 + sseg * 16)     = kr[0];
    *(s16x8*)(Kb + skey * 72 + sseg * 16 + 8) = kr[1];
    #pragma unroll
    for (int half = 0; half < 2; half++)
      #pragma unroll
      for (int j = 0; j < 8; j++){
        const int d = sseg * 16 + half * 8 + j;
        Vb[d * 64 + (((skey & 56) ^ ((d & 7) << 3)) | (skey & 7))] = vr[half][j];
      }
    if (tb < 7) issue(jb + 64);
    __syncthreads();

    const bool act = (jb >= 0) && (jb <= i0 + 63) && (jb + 63 >= i0 - 255) &&
                     (((unsigned)i0 & lm) == ((unsigned)jb & lm));
    if (!act) continue;

    #pragma unroll
    for (int rt = 0; rt < 4; rt++){
      const int ilo = i0 + rt * 16;
      if (ilo + 15 < jb || ilo - (jb + 63) >= WIN) continue;
      f32x4 sc[4];
      #pragma unroll
      for (int ct = 0; ct < 4; ct++){
        const short* kbase = Kb + (ct * 16 + l15) * 72 + quad * 8;
        const s16x8 b0 = *(const s16x8*)(kbase);
        const s16x8 b1 = *(const s16x8*)(kbase + 32);
        f32x4 aa = (f32x4){0,0,0,0};
        aa = __builtin_amdgcn_mfma_f32_16x16x32_bf16(qf[rt][0], b0, aa, 0, 0, 0);
        aa = __builtin_amdgcn_mfma_f32_16x16x32_bf16(qf[rt][1], b1, aa, 0, 0, 0);
        sc[ct] = aa;
      }
      float alph[4];
      #pragma unroll
      for (int r = 0; r < 4; r++){
        const int i = ilo + quad * 4 + r;
        #pragma unroll
        for (int ct = 0; ct < 4; ct++){
          const unsigned dd = (unsigned)(i - (jb + ct * 16 + l15));
          if (dd >= 256u) sc[ct][r] = -1e30f;
        }
        float mx = fmaxf(fmaxf(sc[0][r], sc[1][r]), fmaxf(sc[2][r], sc[3][r]));
        mx = fmaxf(mx, __shfl_xor(mx, 1));
        mx = fmaxf(mx, __shfl_xor(mx, 2));
        mx = fmaxf(mx, __shfl_xor(mx, 4));
        mx = fmaxf(mx, __shfl_xor(mx, 8));
        const float mnew = fmaxf(mm[rt][r], mx);
        alph[r] = __expf(mm[rt][r] - mnew);
        mm[rt][r] = mnew;
        float p0 = __expf(sc[0][r] - mnew);
        float p1 = __expf(sc[1][r] - mnew);
        float p2 = __expf(sc[2][r] - mnew);
        float p3 = __expf(sc[3][r] - mnew);
        sc[0][r] = p0; sc[1][r] = p1; sc[2][r] = p2; sc[3][r] = p3;
        float rsum = (p0 + p1) + (p2 + p3);
        rsum += __shfl_xor(rsum, 1);
        rsum += __shfl_xor(rsum, 2);
        rsum += __shfl_xor(rsum, 4);
        rsum += __shfl_xor(rsum, 8);
        ll[rt][r] = ll[rt][r] * alph[r] + rsum;
      }
      #pragma unroll
      for (int co = 0; co < 4; co++)
        #pragma unroll
        for (int r = 0; r < 4; r++) O[rt][co][r] *= alph[r];
      #pragma unroll
      for (int r = 0; r < 4; r++){
        const int prow = quad * 4 + r;
        #pragma unroll
        for (int ct = 0; ct < 4; ct++)
          myP[prow * 72 + ct * 16 + l15] = (short)f2bf(sc[ct][r]);
      }
      #pragma unroll
      for (int ks2 = 0; ks2 < 2; ks2++){
        const s16x8 pf = *(const s16x8*)(myP + l15 * 72 + ks2 * 32 + quad * 8);
        #pragma unroll
        for (int co = 0; co < 4; co++){
          const int d = co * 16 + l15;
          const s16x8 vf = *(const s16x8*)(Vb + d * 64 +
                              ((ks2 * 32 + quad * 8) ^ ((d & 7) << 3)));
          O[rt][co] = __builtin_amdgcn_mfma_f32_16x16x32_bf16(pf, vf, O[rt][co], 0, 0, 0);
        }
      }
    }
  }

  #pragma unroll
  for (int rt = 0; rt < 4; rt++)
    #pragma unroll
    for (int co = 0; co < 4; co++)
      #pragma unroll
      for (int r = 0; r < 4; r++){
        const int tok = i0 + rt * 16 + quad * 4 + r;
        comb[(size_t)tok * COMBN + h * DHD + co * 16 + l15] = f2bf(O[rt][co][r] / ll[rt][r]);
      }
}

extern "C" void kernel_launch(void* const* d_in, const int* in_sizes, int n_in,
                              void* d_out, int out_size, void* d_ws, size_t ws_size,
                              hipStream_t stream)
{
  const float* x     = (const float*)d_in[0];
  const float* psin  = (const float*)d_in[2];
  const float* pcos  = (const float*)d_in[3];
  const float* lns   = (const float*)d_in[4];
  const float* lno   = (const float*)d_in[5];
  const float* w_in  = (const float*)d_in[6];
  const float* b_in  = (const float*)d_in[7];
  const float* w_out = (const float*)d_in[8];
  const float* b_out = (const float*)d_in[9];
  const int*   lenp  = (const int*)d_in[10];
  float* out = (float*)d_out;

  char* ws = (char*)d_ws;
  size_t off = 0;
  unsigned short* xn    = (unsigned short*)(ws + off); off += (size_t)N_TOK * HIDN * 2;
  unsigned short* wInT  = (unsigned short*)(ws + off); off += (size_t)MIDN * HIDN * 2;
  unsigned short* wOutT = (unsigned short*)(ws + off); off += (size_t)HIDN * COMBN * 2;
  unsigned short* qbuf  = (unsigned short*)(ws + off); off += (size_t)N_TOK * HIDN * 2;
  unsigned short* kbuf  = (unsigned short*)(ws + off); off += (size_t)N_TOK * HIDN * 2;
  unsigned short* vbuf  = (unsigned short*)(ws + off); off += (size_t)N_TOK * HIDN * 2;
  unsigned short* comb  = (unsigned short*)(ws + off); off += (size_t)N_TOK * COMBN * 2;

  transpose_f2b<<<dim3(MIDN/64, HIDN/64), 256, 0, stream>>>(w_in, wInT, HIDN, MIDN);
  transpose_f2b<<<dim3(HIDN/64, COMBN/64), 256, 0, stream>>>(w_out, wOutT, COMBN, HIDN);
  ln_kernel<<<dim3(N_TOK/4), 256, 0, stream>>>(x, lns, lno, xn);
  gemm1_k<<<dim3(MIDN/128, N_TOK/128), 256, 0, stream>>>(
      xn, wInT, b_in, psin, pcos, qbuf, kbuf, vbuf, comb);
  attn_kernel<<<dim3(N_TOK/CHUNK, NH), 256, 0, stream>>>(
      qbuf, kbuf, vbuf, comb, lenp);
  gemm2_k<<<dim3(HIDN/128, N_TOK/128), 256, 0, stream>>>(
      comb, wOutT, b_out, xn, out);
}

// Round 11
// 581.062 us; speedup vs baseline: 1.0471x; 1.0471x over previous
//
#include <hip/hip_runtime.h>

#define N_TOK 16384
#define HIDN  768
#define MIDN  5376
#define COMBN 3840
#define NH    12
#define DHD   64
#define CHUNK 256
#define WIN   256

typedef short s16x8 __attribute__((ext_vector_type(8)));
typedef short s16x4 __attribute__((ext_vector_type(4)));
typedef float f32x4 __attribute__((ext_vector_type(4)));

__device__ __forceinline__ float bf2f(unsigned short u){
  union { unsigned u; float f; } x; x.u = ((unsigned)u) << 16; return x.f;
}
__device__ __forceinline__ unsigned short f2bf(float f){
  union { float f; unsigned u; } x; x.f = f;
  unsigned r = x.u + 0x7fffu + ((x.u >> 16) & 1u);
  return (unsigned short)(r >> 16);
}
__device__ __forceinline__ float gelu_fast(float x){
  float u = -1.5957691216057308f * (x + 0.044715f * x * x * x);
  return x / (1.f + __expf(u));
}
__device__ __forceinline__ void glds16(const void* g, void* l){
  __builtin_amdgcn_global_load_lds(
      (const __attribute__((address_space(1))) unsigned*)g,
      (__attribute__((address_space(3))) unsigned*)l, 16, 0, 0);
}

// ------- transpose + downcast: in fp32 [R][Cc] -> out bf16 [Cc][R] -------
__global__ __launch_bounds__(256) void transpose_f2b(
    const float* __restrict__ in, unsigned short* __restrict__ out,
    int R, int Cc)
{
  __shared__ short t[64 * 72];
  const int tid = threadIdx.x;
  const int r0 = blockIdx.y * 64, c0 = blockIdx.x * 64;
  #pragma unroll
  for (int rep = 0; rep < 4; rep++){
    int v = tid + 256 * rep;
    int r = v >> 4, s = v & 15;
    float4 d = *(const float4*)(in + (size_t)(r0 + r) * Cc + c0 + s * 4);
    s16x4 o = { (short)f2bf(d.x), (short)f2bf(d.y), (short)f2bf(d.z), (short)f2bf(d.w) };
    *(s16x4*)(t + r * 72 + s * 4) = o;
  }
  __syncthreads();
  #pragma unroll
  for (int rep = 0; rep < 2; rep++){
    int v = tid + 256 * rep;
    int c = v & 63, s2 = v >> 6;
    s16x8 d;
    #pragma unroll
    for (int j = 0; j < 8; j++) d[j] = t[(s2 * 8 + j) * 72 + c];
    *(s16x8*)(out + (size_t)(c0 + c) * R + r0 + s2 * 8) = d;
  }
}

// ------- layernorm: fp32 in -> bf16 out, one wave per row -------
__global__ __launch_bounds__(256) void ln_kernel(
    const float* __restrict__ x, const float* __restrict__ sc,
    const float* __restrict__ ofs, unsigned short* __restrict__ xn)
{
  const int lane = threadIdx.x & 63, wv = threadIdx.x >> 6;
  const int row = blockIdx.x * 4 + wv;
  const float4* xr = (const float4*)(x + (size_t)row * HIDN);
  float4 vals[3];
  float sum = 0.f, sq = 0.f;
  #pragma unroll
  for (int j = 0; j < 3; j++){
    vals[j] = xr[lane + 64 * j];
    sum += vals[j].x + vals[j].y + vals[j].z + vals[j].w;
    sq  += vals[j].x * vals[j].x + vals[j].y * vals[j].y
         + vals[j].z * vals[j].z + vals[j].w * vals[j].w;
  }
  #pragma unroll
  for (int o = 1; o < 64; o <<= 1){ sum += __shfl_xor(sum, o); sq += __shfl_xor(sq, o); }
  const float mu = sum * (1.f / HIDN);
  const float rs = rsqrtf(fmaxf(sq * (1.f / HIDN) - mu * mu, 0.f) + 1e-5f);
  s16x4* xo = (s16x4*)(xn + (size_t)row * HIDN);
  const float4* scp = (const float4*)sc;
  const float4* ofp = (const float4*)ofs;
  #pragma unroll
  for (int j = 0; j < 3; j++){
    int p = lane + 64 * j;
    float4 s = scp[p], o = ofp[p];
    s16x4 w;
    w[0] = (short)f2bf((vals[j].x - mu) * rs * s.x + o.x);
    w[1] = (short)f2bf((vals[j].y - mu) * rs * s.y + o.y);
    w[2] = (short)f2bf((vals[j].z - mu) * rs * s.z + o.z);
    w[3] = (short)f2bf((vals[j].w - mu) * rs * s.w + o.w);
    xo[p] = w;
  }
}

// ============================================================================
// R11 GEMM pipe: 128(M) x 256(N) tile, 256 threads = 4 waves (2Mx2N),
// per-wave 64x128 output = acc[4][8]. This cuts LDS bytes/FLOP by 25% vs the
// 64x64 shape that pinned MfmaUtil at ~30% in R6-R10 (LDS data path was the
// ceiling: reads 12 b128/32 MFMA instead of 8/16).
// BK=32, 3 LDS buffers of 24 KiB (A 8K + B 16K) = 72 KiB -> 2 blocks/CU.
// Phase t: {32 MFMA (setprio) | vmcnt(6) | barrier | rdfrags(t+1) |
//           stage(t+3)}.
// Counting: at phase-t wait, outstanding = tiles t+1,t+2 (6 loads each,
// staged at tails of t-2,t-1) = 12 -> vmcnt(6) lands t+1, keeps t+2 flying.
// WAR-safety of stage(t+3)->buf[t%3]: the last reads of buf[t%3] are the
// frag ds_reads consumed by THIS phase's MFMAs; each wave's reads complete
// before its MFMA issues (hw lgkmcnt), MFMA issue precedes the barrier, and
// stage(t+3) is issued after the barrier -> all waves' reads are complete.
// Swizzle (verified R6-R10, conflicts=0): 64B rows, phys seg=seg^((row>>1)&3),
// inverse on global source col ksw=((tid&3)^((tid>>3)&3))*8 elems.
// ============================================================================
template<int K>
__device__ __forceinline__ void gemm_pipe4(
    const unsigned short* __restrict__ A, const unsigned short* __restrict__ BT,
    short* SM,   // 36864 shorts = 72 KiB: buf b at b*24576B; A +0, B +8192B
    int tid, int quad, int l15, int wr, int wc, int m0, int n0,
    f32x4 acc[4][8])
{
  constexpr int T = K / 32;
  char* const SMc = (char*)SM;
  const int srow = tid >> 2;
  const int ksw  = ((tid & 3) ^ ((tid >> 3) & 3)) * 8;
  const unsigned short* Ap = A  + (size_t)(m0 + srow) * K + ksw;
  const unsigned short* Bp = BT + (size_t)(n0 + srow) * K + ksw;
  const size_t rstep = (size_t)64 * K;

  const int segx = ((quad ^ ((l15 >> 1) & 3)) << 4);
  int offA[4], offB[8];
  #pragma unroll
  for (int mf = 0; mf < 4; mf++) offA[mf] = (wr * 64 + mf * 16 + l15) * 64 + segx;
  #pragma unroll
  for (int nf = 0; nf < 8; nf++) offB[nf] = 8192 + (wc * 128 + nf * 16 + l15) * 64 + segx;

  auto stage = [&](int tt){
    const int b = tt % 3;
    char* Ad = SMc + b * 24576 + tid * 16;
    char* Bd = SMc + b * 24576 + 8192 + tid * 16;
    const unsigned short* As = Ap + tt * 32;
    const unsigned short* Bs = Bp + tt * 32;
    glds16(As,         Ad);
    glds16(As + rstep, Ad + 4096);
    #pragma unroll
    for (int r = 0; r < 4; r++)
      glds16(Bs + r * rstep, Bd + r * 4096);
  };

  s16x8 af[4], bf[8];
  auto rdfrags = [&](int b){
    const char* Bb = SMc + b * 24576;
    #pragma unroll
    for (int i = 0; i < 4; i++) af[i] = *(const s16x8*)(Bb + offA[i]);
    #pragma unroll
    for (int j = 0; j < 8; j++) bf[j] = *(const s16x8*)(Bb + offB[j]);
  };

  stage(0); stage(1); stage(2);
  asm volatile("s_waitcnt vmcnt(12)" ::: "memory");   // tile 0 landed; 1,2 fly
  asm volatile("s_barrier" ::: "memory");
  rdfrags(0);

  #pragma unroll 3
  for (int t = 0; t < T; ++t){
    __builtin_amdgcn_s_setprio(1);
    #pragma unroll
    for (int i = 0; i < 4; i++)
      #pragma unroll
      for (int j = 0; j < 8; j++)
        acc[i][j] = __builtin_amdgcn_mfma_f32_16x16x32_bf16(af[i], bf[j], acc[i][j], 0, 0, 0);
    __builtin_amdgcn_s_setprio(0);
    if (t + 1 < T){
      if (t + 2 < T){ asm volatile("s_waitcnt vmcnt(6)" ::: "memory"); }
      else          { asm volatile("s_waitcnt vmcnt(0)" ::: "memory"); }
      asm volatile("s_barrier" ::: "memory");
      rdfrags((t + 1) % 3);
      if (t + 3 < T) stage(t + 3);
    }
  }
}

// ------- GEMM1: [16384x768] x [5376x768]^T -> q(rope)/k(rope)/v/comb(gelu) ---
__global__ __launch_bounds__(256, 2) void gemm1_k(
    const unsigned short* __restrict__ A, const unsigned short* __restrict__ BT,
    const float* __restrict__ bias,
    const float* __restrict__ psin, const float* __restrict__ pcos,
    unsigned short* __restrict__ qb, unsigned short* __restrict__ kb,
    unsigned short* __restrict__ vb, unsigned short* __restrict__ comb)
{
  __shared__ short SM[36864];
  const int tid = threadIdx.x, lane = tid & 63, wv = tid >> 6;
  const int quad = lane >> 4, l15 = lane & 15;
  const int wr = wv >> 1, wc = wv & 1;

  // supertile remap (measured best, R8): GROUP_M=16 m-rows per super-row
  const int nbx = gridDim.x;                    // 21
  const int bid = blockIdx.x + blockIdx.y * nbx;
  const int GM = 16;
  const int group = bid / (GM * nbx);
  const int rem   = bid % (GM * nbx);
  const int m0 = (group * GM + (rem % GM)) * 128;
  const int n0 = (rem / GM) * 256;

  f32x4 acc[4][8];
  #pragma unroll
  for (int i = 0; i < 4; i++)
    #pragma unroll
    for (int j = 0; j < 8; j++) acc[i][j] = (f32x4){0.f,0.f,0.f,0.f};

  gemm_pipe4<HIDN>(A, BT, SM, tid, quad, l15, wr, wc, m0, n0, acc);

  // block-uniform output class (boundaries 768/1536/2304 are multiples of 256)
  unsigned short* dstb; int cb; int cls;
  if (n0 < 768)       { dstb = qb;   cb = n0;        cls = 0; }
  else if (n0 < 1536) { dstb = kb;   cb = n0 - 768;  cls = 1; }
  else if (n0 < 2304) { dstb = vb;   cb = n0 - 1536; cls = 2; }
  else                { dstb = comb; cb = n0 - 1536; cls = 3; }
  const int rowstride = (cls == 3) ? COMBN : HIDN;

  float bsv[8];
  #pragma unroll
  for (int nf = 0; nf < 8; nf++) bsv[nf] = bias[n0 + wc * 128 + nf * 16 + l15];

  if (cls <= 1){
    // q/k: fused RoPE (+1/8 scale for q). col pair c^1 -> lane l15^1 (same
    // nf): one shfl_xor. d = col%64 = (nf&3)*16 + l15 (cb, wc*128 mult of 64).
    const float qscale = (cls == 0) ? 0.125f : 1.0f;
    #pragma unroll
    for (int mf = 0; mf < 4; mf++){
      #pragma unroll
      for (int r = 0; r < 4; r++){
        const int row = m0 + wr * 64 + mf * 16 + quad * 4 + r;
        unsigned short* rp = dstb + (size_t)row * rowstride + cb + wc * 128;
        const float* sp = psin + (size_t)row * DHD;
        const float* cp = pcos + (size_t)row * DHD;
        #pragma unroll
        for (int nf = 0; nf < 8; nf++){
          const int d = (nf & 3) * 16 + l15;
          float v = acc[mf][nf][r] + bsv[nf];
          float vp = __shfl_xor(v, 1);
          const float s = sp[d], c = cp[d];
          float o = (l15 & 1) ? (v * c + vp * s) : (v * c - vp * s);
          rp[nf * 16 + l15] = f2bf(o * qscale);
        }
      }
    }
  } else {
    // v / ff: nf-INNER contiguous 256B row-runs (full-line writes)
    #pragma unroll
    for (int mf = 0; mf < 4; mf++){
      #pragma unroll
      for (int r = 0; r < 4; r++){
        const int row = m0 + wr * 64 + mf * 16 + quad * 4 + r;
        unsigned short* rp = dstb + (size_t)row * rowstride + cb + wc * 128;
        #pragma unroll
        for (int nf = 0; nf < 8; nf++){
          float val = acc[mf][nf][r] + bsv[nf];
          if (cls == 3) val = gelu_fast(val);
          rp[nf * 16 + l15] = f2bf(val);
        }
      }
    }
  }
}

// ------- GEMM2: [16384x3840] x [768x3840]^T + b + xn residual -> fp32 -------
__global__ __launch_bounds__(256, 2) void gemm2_k(
    const unsigned short* __restrict__ A, const unsigned short* __restrict__ BT,
    const float* __restrict__ bias, const unsigned short* __restrict__ xn,
    float* __restrict__ outp)
{
  __shared__ short SM[36864];
  const int tid = threadIdx.x, lane = tid & 63, wv = tid >> 6;
  const int quad = lane >> 4, l15 = lane & 15;
  const int wr = wv >> 1, wc = wv & 1;
  const int n0 = blockIdx.x * 256, m0 = blockIdx.y * 128;

  f32x4 acc[4][8];
  #pragma unroll
  for (int i = 0; i < 4; i++)
    #pragma unroll
    for (int j = 0; j < 8; j++) acc[i][j] = (f32x4){0.f,0.f,0.f,0.f};

  gemm_pipe4<COMBN>(A, BT, SM, tid, quad, l15, wr, wc, m0, n0, acc);

  float bsv[8];
  #pragma unroll
  for (int nf = 0; nf < 8; nf++) bsv[nf] = bias[n0 + wc * 128 + nf * 16 + l15];

  #pragma unroll
  for (int mf = 0; mf < 4; mf++){
    #pragma unroll
    for (int r = 0; r < 4; r++){
      const int row = m0 + wr * 64 + mf * 16 + quad * 4 + r;
      const size_t rb = (size_t)row * HIDN + n0 + wc * 128;
      #pragma unroll
      for (int nf = 0; nf < 8; nf++){
        const size_t o = rb + nf * 16 + l15;
        outp[o] = bf2f(xn[o]) + acc[mf][nf][r] + bsv[nf];
      }
    }
  }
}

// ------- chunked local attention: pre-roped Q/K [tok][768], 64-key tiles -------
__global__ __launch_bounds__(256) void attn_kernel(
    const unsigned short* __restrict__ qb, const unsigned short* __restrict__ kb,
    const unsigned short* __restrict__ vb, unsigned short* __restrict__ comb,
    const int* __restrict__ lenp)
{
  __shared__ short Ks[2][64 * 72];
  __shared__ short Vt[2][64 * 64];
  __shared__ short Ps[4][16 * 72];
  const int tid = threadIdx.x, lane = tid & 63, wv = tid >> 6;
  const int quad = lane >> 4, l15 = lane & 15;
  const int h = blockIdx.y, c = blockIdx.x;
  const unsigned lm = ~((unsigned)lenp[0] - 1u);
  const int i0 = c * CHUNK + wv * 64;
  const unsigned short* qh = qb + h * DHD;
  const unsigned short* kh = kb + h * DHD;
  const unsigned short* vh = vb + h * DHD;

  s16x8 qf[4][2];
  #pragma unroll
  for (int rt = 0; rt < 4; rt++){
    const unsigned short* qr = qh + (size_t)(i0 + rt * 16 + l15) * HIDN;
    qf[rt][0] = *(const s16x8*)(qr + quad * 8);
    qf[rt][1] = *(const s16x8*)(qr + 32 + quad * 8);
  }

  f32x4 O[4][4];
  float mm[4][4], ll[4][4];
  #pragma unroll
  for (int rt = 0; rt < 4; rt++)
    #pragma unroll
    for (int j = 0; j < 4; j++){ O[rt][j] = (f32x4){0,0,0,0}; mm[rt][j] = -1e30f; ll[rt][j] = 0.f; }
  short* myP = &Ps[wv][0];

  const int skey = tid & 63, sseg = tid >> 6;
  const int jb0 = c * CHUNK - 256;
  s16x8 kr[2], vr[2];

  auto issue = [&](int jb){
    if (jb >= 0){
      const unsigned short* kp = kh + (size_t)(jb + skey) * HIDN + sseg * 16;
      const unsigned short* vp = vh + (size_t)(jb + skey) * HIDN + sseg * 16;
      kr[0] = *(const s16x8*)(kp);     kr[1] = *(const s16x8*)(kp + 8);
      vr[0] = *(const s16x8*)(vp);     vr[1] = *(const s16x8*)(vp + 8);
    } else {
      kr[0] = kr[1] = vr[0] = vr[1] = (s16x8){0,0,0,0,0,0,0,0};
    }
  };

  issue(jb0);
  for (int tb = 0; tb < 8; tb++){
    const int jb = jb0 + tb * 64;
    const int buf = tb & 1;
    short* Kb = &Ks[buf][0];
    short* Vb = &Vt[buf][0];
    *(s16x8*)(Kb + skey * 72 + sseg * 16)     = kr[0];
    *(s16x8*)(Kb + skey * 72 + sseg * 16 + 8) = kr[1];
    #pragma unroll
    for (int half = 0; half < 2; half++)
      #pragma unroll
      for (int j = 0; j < 8; j++){
        const int d = sseg * 16 + half * 8 + j;
        Vb[d * 64 + (((skey & 56) ^ ((d & 7) << 3)) | (skey & 7))] = vr[half][j];
      }
    if (tb < 7) issue(jb + 64);
    __syncthreads();

    const bool act = (jb >= 0) && (jb <= i0 + 63) && (jb + 63 >= i0 - 255) &&
                     (((unsigned)i0 & lm) == ((unsigned)jb & lm));
    if (!act) continue;

    #pragma unroll
    for (int rt = 0; rt < 4; rt++){
      const int ilo = i0 + rt * 16;
      if (ilo + 15 < jb || ilo - (jb + 63) >= WIN) continue;
      f32x4 sc[4];
      #pragma unroll
      for (int ct = 0; ct < 4; ct++){
        const short* kbase = Kb + (ct * 16 + l15) * 72 + quad * 8;
        const s16x8 b0 = *(const s16x8*)(kbase);
        const s16x8 b1 = *(const s16x8*)(kbase + 32);
        f32x4 aa = (f32x4){0,0,0,0};
        aa = __builtin_amdgcn_mfma_f32_16x16x32_bf16(qf[rt][0], b0, aa, 0, 0, 0);
        aa = __builtin_amdgcn_mfma_f32_16x16x32_bf16(qf[rt][1], b1, aa, 0, 0, 0);
        sc[ct] = aa;
      }
      float alph[4];
      #pragma unroll
      for (int r = 0; r < 4; r++){
        const int i = ilo + quad * 4 + r;
        #pragma unroll
        for (int ct = 0; ct < 4; ct++){
          const unsigned dd = (unsigned)(i - (jb + ct * 16 + l15));
          if (dd >= 256u) sc[ct][r] = -1e30f;
        }
        float mx = fmaxf(fmaxf(sc[0][r], sc[1][r]), fmaxf(sc[2][r], sc[3][r]));
        mx = fmaxf(mx, __shfl_xor(mx, 1));
        mx = fmaxf(mx, __shfl_xor(mx, 2));
        mx = fmaxf(mx, __shfl_xor(mx, 4));
        mx = fmaxf(mx, __shfl_xor(mx, 8));
        const float mnew = fmaxf(mm[rt][r], mx);
        alph[r] = __expf(mm[rt][r] - mnew);
        mm[rt][r] = mnew;
        float p0 = __expf(sc[0][r] - mnew);
        float p1 = __expf(sc[1][r] - mnew);
        float p2 = __expf(sc[2][r] - mnew);
        float p3 = __expf(sc[3][r] - mnew);
        sc[0][r] = p0; sc[1][r] = p1; sc[2][r] = p2; sc[3][r] = p3;
        float rsum = (p0 + p1) + (p2 + p3);
        rsum += __shfl_xor(rsum, 1);
        rsum += __shfl_xor(rsum, 2);
        rsum += __shfl_xor(rsum, 4);
        rsum += __shfl_xor(rsum, 8);
        ll[rt][r] = ll[rt][r] * alph[r] + rsum;
      }
      #pragma unroll
      for (int co = 0; co < 4; co++)
        #pragma unroll
        for (int r = 0; r < 4; r++) O[rt][co][r] *= alph[r];
      #pragma unroll
      for (int r = 0; r < 4; r++){
        const int prow = quad * 4 + r;
        #pragma unroll
        for (int ct = 0; ct < 4; ct++)
          myP[prow * 72 + ct * 16 + l15] = (short)f2bf(sc[ct][r]);
      }
      #pragma unroll
      for (int ks2 = 0; ks2 < 2; ks2++){
        const s16x8 pf = *(const s16x8*)(myP + l15 * 72 + ks2 * 32 + quad * 8);
        #pragma unroll
        for (int co = 0; co < 4; co++){
          const int d = co * 16 + l15;
          const s16x8 vf = *(const s16x8*)(Vb + d * 64 +
                              ((ks2 * 32 + quad * 8) ^ ((d & 7) << 3)));
          O[rt][co] = __builtin_amdgcn_mfma_f32_16x16x32_bf16(pf, vf, O[rt][co], 0, 0, 0);
        }
      }
    }
  }

  #pragma unroll
  for (int rt = 0; rt < 4; rt++)
    #pragma unroll
    for (int co = 0; co < 4; co++)
      #pragma unroll
      for (int r = 0; r < 4; r++){
        const int tok = i0 + rt * 16 + quad * 4 + r;
        comb[(size_t)tok * COMBN + h * DHD + co * 16 + l15] = f2bf(O[rt][co][r] / ll[rt][r]);
      }
}

extern "C" void kernel_launch(void* const* d_in, const int* in_sizes, int n_in,
                              void* d_out, int out_size, void* d_ws, size_t ws_size,
                              hipStream_t stream)
{
  const float* x     = (const float*)d_in[0];
  const float* psin  = (const float*)d_in[2];
  const float* pcos  = (const float*)d_in[3];
  const float* lns   = (const float*)d_in[4];
  const float* lno   = (const float*)d_in[5];
  const float* w_in  = (const float*)d_in[6];
  const float* b_in  = (const float*)d_in[7];
  const float* w_out = (const float*)d_in[8];
  const float* b_out = (const float*)d_in[9];
  const int*   lenp  = (const int*)d_in[10];
  float* out = (float*)d_out;

  char* ws = (char*)d_ws;
  size_t off = 0;
  unsigned short* xn    = (unsigned short*)(ws + off); off += (size_t)N_TOK * HIDN * 2;
  unsigned short* wInT  = (unsigned short*)(ws + off); off += (size_t)MIDN * HIDN * 2;
  unsigned short* wOutT = (unsigned short*)(ws + off); off += (size_t)HIDN * COMBN * 2;
  unsigned short* qbuf  = (unsigned short*)(ws + off); off += (size_t)N_TOK * HIDN * 2;
  unsigned short* kbuf  = (unsigned short*)(ws + off); off += (size_t)N_TOK * HIDN * 2;
  unsigned short* vbuf  = (unsigned short*)(ws + off); off += (size_t)N_TOK * HIDN * 2;
  unsigned short* comb  = (unsigned short*)(ws + off); off += (size_t)N_TOK * COMBN * 2;

  transpose_f2b<<<dim3(MIDN/64, HIDN/64), 256, 0, stream>>>(w_in, wInT, HIDN, MIDN);
  transpose_f2b<<<dim3(HIDN/64, COMBN/64), 256, 0, stream>>>(w_out, wOutT, COMBN, HIDN);
  ln_kernel<<<dim3(N_TOK/4), 256, 0, stream>>>(x, lns, lno, xn);
  gemm1_k<<<dim3(MIDN/256, N_TOK/128), 256, 0, stream>>>(
      xn, wInT, b_in, psin, pcos, qbuf, kbuf, vbuf, comb);
  attn_kernel<<<dim3(N_TOK/CHUNK, NH), 256, 0, stream>>>(
      qbuf, kbuf, vbuf, comb, lenp);
  gemm2_k<<<dim3(HIDN/256, N_TOK/128), 256, 0, stream>>>(
      comb, wOutT, b_out, xn, out);
}